// Round 7
// baseline (237.113 us; speedup 1.0000x reference)
//
#include <hip/hip_runtime.h>
#include <hip/hip_bf16.h>
#include <math.h>

#define T_TOK 4096
#define D_EMB 768
#define DFF   3072
#define N_EXP 8
#define MAXT  72   // max row-tiles: 8192/128 + 8 partials
#define CNTS  16   // cnt padding stride (ints) -> one 64B line per expert

typedef __attribute__((ext_vector_type(8))) short bf16x8;
typedef __attribute__((ext_vector_type(4))) float f32x4;

typedef __attribute__((address_space(3))) unsigned int lds_u32_t;
typedef __attribute__((address_space(1))) unsigned int glob_u32_t;

__device__ __forceinline__ void gload16(const void* g, void* l) {
  __builtin_amdgcn_global_load_lds((const glob_u32_t*)g, (lds_u32_t*)l, 16, 0, 0);
}

__device__ __forceinline__ short f2bf(float f) {
  union { __hip_bfloat16 b; short s; } u;
  u.b = __float2bfloat16(f);
  return u.s;
}

// ---------------- zero out + counters ----------------
__global__ void zero_init_kernel(float4* __restrict__ out4, int n4, int* __restrict__ cnt) {
  int i = blockIdx.x * blockDim.x + threadIdx.x;
  if (i < N_EXP * CNTS) cnt[i] = 0;
  float4 z; z.x = z.y = z.z = z.w = 0.f;
  for (int j = i; j < n4; j += gridDim.x * blockDim.x) out4[j] = z;
}

// ---------------- x fp32 -> bf16 ----------------
__global__ void cast_x_kernel(const float4* __restrict__ in, short4* __restrict__ outp, int n4) {
  int i = blockIdx.x * blockDim.x + threadIdx.x;
  if (i >= n4) return;
  float4 v = in[i];
  short4 o;
  o.x = f2bf(v.x); o.y = f2bf(v.y); o.z = f2bf(v.z); o.w = f2bf(v.w);
  outp[i] = o;
}

// ---------------- weight transpose+cast: [e][R][C] f32 -> [e][C][R] bf16 ----------------
__global__ void transpose_cast_kernel(const float* __restrict__ in, short* __restrict__ outp,
                                      int R, int C) {
  __shared__ float tile[64][65];
  int e = blockIdx.z;
  int c0 = blockIdx.x * 64, r0 = blockIdx.y * 64;
  const float* src = in + (size_t)e * R * C;
  short* dst = outp + (size_t)e * R * C;
  int tid = threadIdx.x;
#pragma unroll
  for (int it = 0; it < 4; ++it) {
    int idx = tid + it * 256;
    int r = idx >> 4;
    int c4 = idx & 15;
    float4 v = *(const float4*)&src[(size_t)(r0 + r) * C + c0 + c4 * 4];
    tile[r][c4 * 4 + 0] = v.x; tile[r][c4 * 4 + 1] = v.y;
    tile[r][c4 * 4 + 2] = v.z; tile[r][c4 * 4 + 3] = v.w;
  }
  __syncthreads();
#pragma unroll
  for (int it = 0; it < 4; ++it) {
    int idx = tid + it * 256;
    int c = idx >> 4;
    int rr = idx & 15;
    short4 o;
    o.x = f2bf(tile[rr * 4 + 0][c]);
    o.y = f2bf(tile[rr * 4 + 1][c]);
    o.z = f2bf(tile[rr * 4 + 2][c]);
    o.w = f2bf(tile[rr * 4 + 3][c]);
    *(short4*)&dst[(size_t)(c0 + c) * R + r0 + rr * 4] = o;
  }
}

// ---------------- gate: 16 tokens/block, LDS-aggregated routing ----------------
__global__ __launch_bounds__(256)
void gate_kernel(const float* __restrict__ x, const float* __restrict__ gw,
                 int* __restrict__ cnt, int* __restrict__ tok,
                 float* __restrict__ wgt) {
  __shared__ int lcnt[N_EXP];
  __shared__ int gbase[N_EXP];
  __shared__ int le[32];
  __shared__ float lw[32];
  __shared__ int lpos[32];
  int tid = threadIdx.x, lane = tid & 63, wid = tid >> 6;
  if (tid < N_EXP) lcnt[tid] = 0;
  __syncthreads();

#pragma unroll
  for (int i = 0; i < 4; i++) {
    int t = blockIdx.x * 16 + wid * 4 + i;
    float s[N_EXP];
#pragma unroll
    for (int e = 0; e < N_EXP; e++) s[e] = 0.f;
#pragma unroll
    for (int dd = 0; dd < D_EMB / 64; dd++) {
      int d = dd * 64 + lane;
      float xv = x[(size_t)t * D_EMB + d];
#pragma unroll
      for (int e = 0; e < N_EXP; e++) s[e] += xv * gw[d * N_EXP + e];
    }
#pragma unroll
    for (int e = 0; e < N_EXP; e++) {
#pragma unroll
      for (int off = 32; off > 0; off >>= 1) s[e] += __shfl_xor(s[e], off, 64);
    }
    if (lane == 0) {
      int e0 = 0;
#pragma unroll
      for (int e = 1; e < N_EXP; e++) if (s[e] > s[e0]) e0 = e;
      int e1 = -1;
#pragma unroll
      for (int e = 0; e < N_EXP; e++) {
        if (e == e0) continue;
        if (e1 < 0 || s[e] > s[e1]) e1 = e;
      }
      float p1 = __expf(s[e1] - s[e0]);
      float inv = 1.f / (1.f + p1);
      int idx = (wid * 4 + i) * 2;
      le[idx] = e0; lw[idx] = inv;           lpos[idx] = atomicAdd(&lcnt[e0], 1);
      le[idx + 1] = e1; lw[idx + 1] = p1 * inv; lpos[idx + 1] = atomicAdd(&lcnt[e1], 1);
    }
  }
  __syncthreads();
  if (tid < N_EXP) gbase[tid] = atomicAdd(&cnt[tid * CNTS], lcnt[tid]);
  __syncthreads();
  if (tid < 32) {
    int e = le[tid];
    int t = blockIdx.x * 16 + (tid >> 1);
    int p = gbase[e] + lpos[tid];
    tok[e * T_TOK + p] = t;
    wgt[e * T_TOK + p] = lw[tid];
  }
}

// ---------------- plan: offsets + compacted (expert, row-tile) list ----------------
__global__ void plan_kernel(const int* __restrict__ cnt, int* __restrict__ offs,
                            int* __restrict__ tile_e, int* __restrict__ tile_rt,
                            int* __restrict__ ntiles) {
  if (threadIdx.x != 0 || blockIdx.x != 0) return;
  int o = 0, nt = 0;
  for (int e = 0; e < N_EXP; e++) {
    offs[e] = o;
    int tc = (cnt[e * CNTS] + 127) >> 7;
    for (int i = 0; i < tc; i++) { tile_e[nt] = e; tile_rt[nt] = i; nt++; }
    o += cnt[e * CNTS];
  }
  *ntiles = nt;
}

// ---------------- grouped GEMM, 128x128 tile, BK=32, dbuf LDS (32 KiB) ----------------
// Occupancy-first: 32 KiB LDS + launch_bounds(256,4) -> 4+ blocks/CU so cross-block
// TLP hides the per-step vmcnt drain (m97/m114 mechanism).
// Swizzle: 64B rows, bank=(16*row+4*slot)%32 -> fold row bit2: q = p ^ ((row^(row>>2))&3).
template<int KDIM, int NDIM, int EPI>
__global__ __launch_bounds__(256, 4)
void moe_gemm(const short* __restrict__ A, const short* __restrict__ Bw,
              const int* __restrict__ tok, const float* __restrict__ wgt,
              const int* __restrict__ cnt, const int* __restrict__ offs,
              const int* __restrict__ tile_e, const int* __restrict__ tile_rt,
              const int* __restrict__ ntiles,
              short* __restrict__ hout, float* __restrict__ fout) {
  const int COLT = NDIM / 128;
  int nwg = gridDim.x;
  int cpx = nwg >> 3;
  int logical = (blockIdx.x & 7) * cpx + (blockIdx.x >> 3);
  int tile = logical / COLT, ct = logical % COLT;
  if (tile >= *ntiles) return;
  int e = tile_e[tile], rt = tile_rt[tile];
  int ne = cnt[e * CNTS];
  int base = offs[e];

  __shared__ __align__(16) short As[2][128 * 32];
  __shared__ __align__(16) short Bs[2][128 * 32];

  int tid = threadIdx.x;
  int lane = tid & 63;
  int wid = tid >> 6;

  // staging map: seg in [0,512), row = seg>>2, physical slot p = seg&3 holds
  // logical 16B k-chunk q = p ^ ((row ^ (row>>2)) & 3); read side same XOR.
  const short* aptr[2];
  const short* bptr[2];
  int lofs[2];
#pragma unroll
  for (int i = 0; i < 2; i++) {
    int seg = tid + i * 256;
    int row = seg >> 2;
    int p = seg & 3;
    int q = p ^ ((row ^ (row >> 2)) & 3);
    int r = rt * 128 + row;
    if (r >= ne) r = ne - 1;
    size_t ga = (EPI == 0) ? (size_t)tok[e * T_TOK + r] : (size_t)(base + r);
    aptr[i] = A + ga * KDIM + q * 8;
    bptr[i] = Bw + ((size_t)e * NDIM + ct * 128 + row) * KDIM + q * 8;
    lofs[i] = seg * 8;
  }

  f32x4 acc[4][4];
#pragma unroll
  for (int m = 0; m < 4; m++)
#pragma unroll
    for (int n = 0; n < 4; n++) acc[m][n] = (f32x4){0.f, 0.f, 0.f, 0.f};

  int wr = (wid >> 1) * 64, wc = (wid & 1) * 64;

  // prologue: stage tile 0 into buf 0
#pragma unroll
  for (int i = 0; i < 2; i++) {
    gload16(aptr[i], &As[0][lofs[i]]);
    gload16(bptr[i], &Bs[0][lofs[i]]);
  }
  __syncthreads();

  const int NKT = KDIM / 32;
  int cur = 0;
  for (int kt = 0; kt < NKT; ++kt) {
    if (kt + 1 < NKT) {
      int k0 = (kt + 1) * 32;
#pragma unroll
      for (int i = 0; i < 2; i++) {
        gload16(aptr[i] + k0, &As[cur ^ 1][lofs[i]]);
        gload16(bptr[i] + k0, &Bs[cur ^ 1][lofs[i]]);
      }
    }
    int cb = lane >> 4;
    bf16x8 af[4], bv[4];
#pragma unroll
    for (int m = 0; m < 4; m++) {
      int row = wr + m * 16 + (lane & 15);
      af[m] = *(const bf16x8*)&As[cur][row * 32 + ((cb ^ ((row ^ (row >> 2)) & 3)) * 8)];
    }
#pragma unroll
    for (int n = 0; n < 4; n++) {
      int row = wc + n * 16 + (lane & 15);
      bv[n] = *(const bf16x8*)&Bs[cur][row * 32 + ((cb ^ ((row ^ (row >> 2)) & 3)) * 8)];
    }
#pragma unroll
    for (int m = 0; m < 4; m++)
#pragma unroll
      for (int n = 0; n < 4; n++)
        acc[m][n] = __builtin_amdgcn_mfma_f32_16x16x32_bf16(af[m], bv[n], acc[m][n], 0, 0, 0);
    __syncthreads();  // drains this wave's prefetch (vmcnt) + LDS reads before swap
    cur ^= 1;
  }

  int colbase = ct * 128 + wc;
#pragma unroll
  for (int m = 0; m < 4; m++) {
#pragma unroll
    for (int j = 0; j < 4; j++) {
      int rloc = rt * 128 + wr + m * 16 + ((lane >> 4) << 2) + j;
      if (rloc < ne) {
        if (EPI == 0) {
          size_t hrow = (size_t)(base + rloc) * NDIM;
#pragma unroll
          for (int n = 0; n < 4; n++) {
            float v = acc[m][n][j];
            float g = 0.5f * v * (1.0f + erff(v * 0.70710678118f));
            hout[hrow + colbase + n * 16 + (lane & 15)] = f2bf(g);
          }
        } else {
          int t = tok[e * T_TOK + rloc];
          float w = wgt[e * T_TOK + rloc];
          float* orow = fout + (size_t)t * NDIM + colbase + (lane & 15);
#pragma unroll
          for (int n = 0; n < 4; n++)
            atomicAdd(orow + n * 16, w * acc[m][n][j]);
        }
      }
    }
  }
}

extern "C" void kernel_launch(void* const* d_in, const int* in_sizes, int n_in,
                              void* d_out, int out_size, void* d_ws, size_t ws_size,
                              hipStream_t stream) {
  const float* x   = (const float*)d_in[0];
  const float* gw  = (const float*)d_in[1];
  const float* wfc = (const float*)d_in[2];
  const float* wpj = (const float*)d_in[3];
  float* out = (float*)d_out;

  char* ws = (char*)d_ws;
  const size_t SZ_XB = (size_t)T_TOK * D_EMB * 2;
  const size_t SZ_W  = (size_t)N_EXP * D_EMB * DFF * 2;
  const size_t SZ_H  = (size_t)2 * T_TOK * DFF * 2;
  short* xb   = (short*)(ws);
  short* wfcT = (short*)(ws + SZ_XB);
  short* wpjT = (short*)(ws + SZ_XB + SZ_W);
  short* h    = (short*)(ws + SZ_XB + 2 * SZ_W);
  char* p2    = ws + SZ_XB + 2 * SZ_W + SZ_H;
  int*   tok  = (int*)(p2);
  float* wgt  = (float*)(p2 + (size_t)N_EXP * T_TOK * 4);
  char* p3    = p2 + (size_t)N_EXP * T_TOK * 8;
  int*   cnt     = (int*)(p3);                     // padded: N_EXP*CNTS ints
  int*   offs    = (int*)(p3 + 1024);
  int*   tile_e  = (int*)(p3 + 1024 + 64);
  int*   tile_rt = (int*)(p3 + 1024 + 64 + 512);
  int*   ntiles  = (int*)(p3 + 1024 + 64 + 1024);

  int n4 = out_size / 4;
  zero_init_kernel<<<2048, 256, 0, stream>>>((float4*)out, n4, cnt);
  cast_x_kernel<<<(T_TOK * D_EMB / 4 + 255) / 256, 256, 0, stream>>>(
      (const float4*)x, (short4*)xb, T_TOK * D_EMB / 4);
  transpose_cast_kernel<<<dim3(DFF / 64, D_EMB / 64, N_EXP), 256, 0, stream>>>(wfc, wfcT, D_EMB, DFF);
  transpose_cast_kernel<<<dim3(D_EMB / 64, DFF / 64, N_EXP), 256, 0, stream>>>(wpj, wpjT, DFF, D_EMB);
  gate_kernel<<<T_TOK / 16, 256, 0, stream>>>(x, gw, cnt, tok, wgt);
  plan_kernel<<<1, 1, 0, stream>>>(cnt, offs, tile_e, tile_rt, ntiles);
  moe_gemm<D_EMB, DFF, 0><<<MAXT * (DFF / 128), 256, 0, stream>>>(
      xb, wfcT, tok, wgt, cnt, offs, tile_e, tile_rt, ntiles, h, nullptr);
  moe_gemm<DFF, D_EMB, 1><<<MAXT * (D_EMB / 128), 256, 0, stream>>>(
      h, wpjT, tok, wgt, cnt, offs, tile_e, tile_rt, ntiles, nullptr, out);
}

// Round 8
// 233.605 us; speedup vs baseline: 1.0150x; 1.0150x over previous
//
#include <hip/hip_runtime.h>
#include <hip/hip_bf16.h>
#include <math.h>

#define T_TOK 4096
#define D_EMB 768
#define DFF   3072
#define N_EXP 8
#define MAXT  72   // max row-tiles: 8192/128 + 8 partials
#define CNTS  16   // cnt padding stride (ints) -> one 64B line per expert

typedef __attribute__((ext_vector_type(8))) short bf16x8;
typedef __attribute__((ext_vector_type(4))) float f32x4;

typedef __attribute__((address_space(3))) unsigned int lds_u32_t;
typedef __attribute__((address_space(1))) unsigned int glob_u32_t;

__device__ __forceinline__ void gload16(const void* g, void* l) {
  __builtin_amdgcn_global_load_lds((const glob_u32_t*)g, (lds_u32_t*)l, 16, 0, 0);
}

__device__ __forceinline__ short f2bf(float f) {
  union { __hip_bfloat16 b; short s; } u;
  u.b = __float2bfloat16(f);
  return u.s;
}

// ---------------- zero out + counters ----------------
__global__ void zero_init_kernel(float4* __restrict__ out4, int n4, int* __restrict__ cnt) {
  int i = blockIdx.x * blockDim.x + threadIdx.x;
  if (i < N_EXP * CNTS) cnt[i] = 0;
  float4 z; z.x = z.y = z.z = z.w = 0.f;
  for (int j = i; j < n4; j += gridDim.x * blockDim.x) out4[j] = z;
}

// ---------------- x fp32 -> bf16 ----------------
__global__ void cast_x_kernel(const float4* __restrict__ in, short4* __restrict__ outp, int n4) {
  int i = blockIdx.x * blockDim.x + threadIdx.x;
  if (i >= n4) return;
  float4 v = in[i];
  short4 o;
  o.x = f2bf(v.x); o.y = f2bf(v.y); o.z = f2bf(v.z); o.w = f2bf(v.w);
  outp[i] = o;
}

// ---------------- weight transpose+cast: [e][R][C] f32 -> [e][C][R] bf16 ----------------
__global__ void transpose_cast_kernel(const float* __restrict__ in, short* __restrict__ outp,
                                      int R, int C) {
  __shared__ float tile[64][65];
  int e = blockIdx.z;
  int c0 = blockIdx.x * 64, r0 = blockIdx.y * 64;
  const float* src = in + (size_t)e * R * C;
  short* dst = outp + (size_t)e * R * C;
  int tid = threadIdx.x;
#pragma unroll
  for (int it = 0; it < 4; ++it) {
    int idx = tid + it * 256;
    int r = idx >> 4;
    int c4 = idx & 15;
    float4 v = *(const float4*)&src[(size_t)(r0 + r) * C + c0 + c4 * 4];
    tile[r][c4 * 4 + 0] = v.x; tile[r][c4 * 4 + 1] = v.y;
    tile[r][c4 * 4 + 2] = v.z; tile[r][c4 * 4 + 3] = v.w;
  }
  __syncthreads();
#pragma unroll
  for (int it = 0; it < 4; ++it) {
    int idx = tid + it * 256;
    int c = idx >> 4;
    int rr = idx & 15;
    short4 o;
    o.x = f2bf(tile[rr * 4 + 0][c]);
    o.y = f2bf(tile[rr * 4 + 1][c]);
    o.z = f2bf(tile[rr * 4 + 2][c]);
    o.w = f2bf(tile[rr * 4 + 3][c]);
    *(short4*)&dst[(size_t)(c0 + c) * R + r0 + rr * 4] = o;
  }
}

// ---------------- gate: 16 tokens/block, LDS-aggregated routing ----------------
__global__ __launch_bounds__(256)
void gate_kernel(const float* __restrict__ x, const float* __restrict__ gw,
                 int* __restrict__ cnt, int* __restrict__ tok,
                 float* __restrict__ wgt) {
  __shared__ int lcnt[N_EXP];
  __shared__ int gbase[N_EXP];
  __shared__ int le[32];
  __shared__ float lw[32];
  __shared__ int lpos[32];
  int tid = threadIdx.x, lane = tid & 63, wid = tid >> 6;
  if (tid < N_EXP) lcnt[tid] = 0;
  __syncthreads();

#pragma unroll
  for (int i = 0; i < 4; i++) {
    int t = blockIdx.x * 16 + wid * 4 + i;
    float s[N_EXP];
#pragma unroll
    for (int e = 0; e < N_EXP; e++) s[e] = 0.f;
#pragma unroll
    for (int dd = 0; dd < D_EMB / 64; dd++) {
      int d = dd * 64 + lane;
      float xv = x[(size_t)t * D_EMB + d];
#pragma unroll
      for (int e = 0; e < N_EXP; e++) s[e] += xv * gw[d * N_EXP + e];
    }
#pragma unroll
    for (int e = 0; e < N_EXP; e++) {
#pragma unroll
      for (int off = 32; off > 0; off >>= 1) s[e] += __shfl_xor(s[e], off, 64);
    }
    if (lane == 0) {
      int e0 = 0;
#pragma unroll
      for (int e = 1; e < N_EXP; e++) if (s[e] > s[e0]) e0 = e;
      int e1 = -1;
#pragma unroll
      for (int e = 0; e < N_EXP; e++) {
        if (e == e0) continue;
        if (e1 < 0 || s[e] > s[e1]) e1 = e;
      }
      float p1 = __expf(s[e1] - s[e0]);
      float inv = 1.f / (1.f + p1);
      int idx = (wid * 4 + i) * 2;
      le[idx] = e0; lw[idx] = inv;           lpos[idx] = atomicAdd(&lcnt[e0], 1);
      le[idx + 1] = e1; lw[idx + 1] = p1 * inv; lpos[idx + 1] = atomicAdd(&lcnt[e1], 1);
    }
  }
  __syncthreads();
  if (tid < N_EXP) gbase[tid] = atomicAdd(&cnt[tid * CNTS], lcnt[tid]);
  __syncthreads();
  if (tid < 32) {
    int e = le[tid];
    int t = blockIdx.x * 16 + (tid >> 1);
    int p = gbase[e] + lpos[tid];
    tok[e * T_TOK + p] = t;
    wgt[e * T_TOK + p] = lw[tid];
  }
}

// ---------------- plan: offsets + compacted (expert, row-tile) list ----------------
__global__ void plan_kernel(const int* __restrict__ cnt, int* __restrict__ offs,
                            int* __restrict__ tile_e, int* __restrict__ tile_rt,
                            int* __restrict__ ntiles) {
  if (threadIdx.x != 0 || blockIdx.x != 0) return;
  int o = 0, nt = 0;
  for (int e = 0; e < N_EXP; e++) {
    offs[e] = o;
    int tc = (cnt[e * CNTS] + 127) >> 7;
    for (int i = 0; i < tc; i++) { tile_e[nt] = e; tile_rt[nt] = i; nt++; }
    o += cnt[e * CNTS];
  }
  *ntiles = nt;
}

// ---------------- grouped GEMM: 128x128 tile, BK=32, TRIPLE-buffer LDS (48 KiB),
// depth-2 prefetch with counted s_waitcnt vmcnt(4) (T3/T4: loads in flight across
// barriers; never drain to 0 in the loop). One raw s_barrier per k-step.
// Correctness: each wave waits vmcnt(4) (own tile-t loads landed) BEFORE the
// barrier; after the barrier tile t is fully in LDS block-wide. Buffer (t+2)%3
// is re-staged only after the barrier that proves step t-1's reads retired.
template<int KDIM, int NDIM, int SPLITK, int EPI>
__global__ __launch_bounds__(256, 3)
void moe_gemm(const short* __restrict__ A, const short* __restrict__ Bw,
              const int* __restrict__ tok, const float* __restrict__ wgt,
              const int* __restrict__ cnt, const int* __restrict__ offs,
              const int* __restrict__ tile_e, const int* __restrict__ tile_rt,
              const int* __restrict__ ntiles,
              short* __restrict__ hout, float* __restrict__ fout) {
  const int COLT = NDIM / 128;
  const int KS = KDIM / SPLITK;     // K-range per block
  const int NKT = KS / 32;          // k-steps (24 FC, 48 PROJ) — multiple of 3
  static_assert(NKT % 3 == 0 && NKT >= 6, "pipeline needs NKT%3==0");

  int nwg = gridDim.x;
  int cpx = nwg >> 3;
  int logical = (blockIdx.x & 7) * cpx + (blockIdx.x >> 3);   // bijective XCD swizzle
  int ct = logical % COLT;
  int tile = (logical / COLT) % MAXT;
  int sk = logical / (COLT * MAXT);
  if (tile >= *ntiles) return;
  int e = tile_e[tile], rt = tile_rt[tile];
  int ne = cnt[e * CNTS];
  int base = offs[e];

  __shared__ __align__(16) short LDS[3 * 2 * 4096];   // 48 KiB
  short* A0 = LDS;              short* B0 = LDS + 4096;
  short* A1 = LDS + 2 * 4096;   short* B1 = LDS + 3 * 4096;
  short* A2 = LDS + 4 * 4096;   short* B2 = LDS + 5 * 4096;

  int tid = threadIdx.x;
  int lane = tid & 63;
  int wid = tid >> 6;

  // staging map: seg in [0,512), row = seg>>2, physical slot p = seg&3 holds
  // logical 16B k-chunk q = p ^ ((row ^ (row>>2)) & 3); read side same XOR.
  const short* aptr0; const short* aptr1;
  const short* bptr0; const short* bptr1;
  int lofs0, lofs1;
  {
    int seg = tid;
    int row = seg >> 2, p = seg & 3;
    int q = p ^ ((row ^ (row >> 2)) & 3);
    int r = rt * 128 + row; if (r >= ne) r = ne - 1;
    size_t ga = (EPI == 0) ? (size_t)tok[e * T_TOK + r] : (size_t)(base + r);
    aptr0 = A + ga * KDIM + sk * KS + q * 8;
    bptr0 = Bw + ((size_t)e * NDIM + ct * 128 + row) * KDIM + sk * KS + q * 8;
    lofs0 = seg * 8;
  }
  {
    int seg = tid + 256;
    int row = seg >> 2, p = seg & 3;
    int q = p ^ ((row ^ (row >> 2)) & 3);
    int r = rt * 128 + row; if (r >= ne) r = ne - 1;
    size_t ga = (EPI == 0) ? (size_t)tok[e * T_TOK + r] : (size_t)(base + r);
    aptr1 = A + ga * KDIM + sk * KS + q * 8;
    bptr1 = Bw + ((size_t)e * NDIM + ct * 128 + row) * KDIM + sk * KS + q * 8;
    lofs1 = seg * 8;
  }

  int wr = (wid >> 1) * 64, wc = (wid & 1) * 64;
  int cb = lane >> 4;

  // loop-invariant LDS read offsets (shorts)
  int offa[4], offb[4];
#pragma unroll
  for (int m = 0; m < 4; m++) {
    int row = wr + m * 16 + (lane & 15);
    offa[m] = row * 32 + (cb ^ ((row ^ (row >> 2)) & 3)) * 8;
  }
#pragma unroll
  for (int n = 0; n < 4; n++) {
    int row = wc + n * 16 + (lane & 15);
    offb[n] = row * 32 + (cb ^ ((row ^ (row >> 2)) & 3)) * 8;
  }

  f32x4 acc[4][4];
#pragma unroll
  for (int m = 0; m < 4; m++)
#pragma unroll
    for (int n = 0; n < 4; n++) acc[m][n] = (f32x4){0.f, 0.f, 0.f, 0.f};

  // prologue: stage tile 0 -> buf0, tile 1 -> buf1 (8 loads outstanding)
  gload16(aptr0, A0 + lofs0); gload16(bptr0, B0 + lofs0);
  gload16(aptr1, A0 + lofs1); gload16(bptr1, B0 + lofs1);
  gload16(aptr0 + 32, A1 + lofs0); gload16(bptr0 + 32, B1 + lofs0);
  gload16(aptr1 + 32, A1 + lofs1); gload16(bptr1 + 32, B1 + lofs1);

#define VMW(N) do { asm volatile("s_waitcnt vmcnt(" #N ")" ::: "memory"); \
                    __builtin_amdgcn_sched_barrier(0); } while (0)
#define STEP(CA, CB, SA, SB, K0, DOSTAGE, WN) do {                          \
    VMW(WN);                                                                \
    __builtin_amdgcn_s_barrier();                                           \
    if (DOSTAGE) {                                                          \
      gload16(aptr0 + (K0), (SA) + lofs0);                                  \
      gload16(bptr0 + (K0), (SB) + lofs0);                                  \
      gload16(aptr1 + (K0), (SA) + lofs1);                                  \
      gload16(bptr1 + (K0), (SB) + lofs1);                                  \
    }                                                                       \
    bf16x8 af_[4], bv_[4];                                                  \
    _Pragma("unroll") for (int m_ = 0; m_ < 4; ++m_)                        \
      af_[m_] = *(const bf16x8*)((CA) + offa[m_]);                          \
    _Pragma("unroll") for (int n_ = 0; n_ < 4; ++n_)                        \
      bv_[n_] = *(const bf16x8*)((CB) + offb[n_]);                          \
    _Pragma("unroll") for (int m_ = 0; m_ < 4; ++m_)                        \
      _Pragma("unroll") for (int n_ = 0; n_ < 4; ++n_)                      \
        acc[m_][n_] = __builtin_amdgcn_mfma_f32_16x16x32_bf16(              \
            af_[m_], bv_[n_], acc[m_][n_], 0, 0, 0);                        \
  } while (0)

  int kb = 64;  // k-offset (shorts) of tile t+2 at t=0
  for (int j = 0; j < NKT / 3 - 1; ++j) {
    STEP(A0, B0, A2, B2, kb,      true, 4);
    STEP(A1, B1, A0, B0, kb + 32, true, 4);
    STEP(A2, B2, A1, B1, kb + 64, true, 4);
    kb += 96;
  }
  STEP(A0, B0, A2, B2, kb, true, 4);   // t=NKT-3: stages last tile
  STEP(A1, B1, A0, B0, 0, false, 4);   // t=NKT-2
  STEP(A2, B2, A1, B1, 0, false, 0);   // t=NKT-1: final drain
#undef STEP
#undef VMW

  int colbase = ct * 128 + wc;
#pragma unroll
  for (int m = 0; m < 4; m++) {
#pragma unroll
    for (int j = 0; j < 4; j++) {
      int rloc = rt * 128 + wr + m * 16 + ((lane >> 4) << 2) + j;
      if (rloc < ne) {
        if (EPI == 0) {
          size_t hrow = (size_t)(base + rloc) * NDIM;
#pragma unroll
          for (int n = 0; n < 4; n++) {
            float v = acc[m][n][j];
            float g = 0.5f * v * (1.0f + erff(v * 0.70710678118f));
            hout[hrow + colbase + n * 16 + (lane & 15)] = f2bf(g);
          }
        } else {
          int t = tok[e * T_TOK + rloc];
          float w = wgt[e * T_TOK + rloc];
          float* orow = fout + (size_t)t * NDIM + colbase + (lane & 15);
#pragma unroll
          for (int n = 0; n < 4; n++)
            atomicAdd(orow + n * 16, w * acc[m][n][j]);
        }
      }
    }
  }
}

extern "C" void kernel_launch(void* const* d_in, const int* in_sizes, int n_in,
                              void* d_out, int out_size, void* d_ws, size_t ws_size,
                              hipStream_t stream) {
  const float* x   = (const float*)d_in[0];
  const float* gw  = (const float*)d_in[1];
  const float* wfc = (const float*)d_in[2];
  const float* wpj = (const float*)d_in[3];
  float* out = (float*)d_out;

  char* ws = (char*)d_ws;
  const size_t SZ_XB = (size_t)T_TOK * D_EMB * 2;
  const size_t SZ_W  = (size_t)N_EXP * D_EMB * DFF * 2;
  const size_t SZ_H  = (size_t)2 * T_TOK * DFF * 2;
  short* xb   = (short*)(ws);
  short* wfcT = (short*)(ws + SZ_XB);
  short* wpjT = (short*)(ws + SZ_XB + SZ_W);
  short* h    = (short*)(ws + SZ_XB + 2 * SZ_W);
  char* p2    = ws + SZ_XB + 2 * SZ_W + SZ_H;
  int*   tok  = (int*)(p2);
  float* wgt  = (float*)(p2 + (size_t)N_EXP * T_TOK * 4);
  char* p3    = p2 + (size_t)N_EXP * T_TOK * 8;
  int*   cnt     = (int*)(p3);                     // padded: N_EXP*CNTS ints
  int*   offs    = (int*)(p3 + 1024);
  int*   tile_e  = (int*)(p3 + 1024 + 64);
  int*   tile_rt = (int*)(p3 + 1024 + 64 + 512);
  int*   ntiles  = (int*)(p3 + 1024 + 64 + 1024);

  int n4 = out_size / 4;
  zero_init_kernel<<<2048, 256, 0, stream>>>((float4*)out, n4, cnt);
  cast_x_kernel<<<(T_TOK * D_EMB / 4 + 255) / 256, 256, 0, stream>>>(
      (const float4*)x, (short4*)xb, T_TOK * D_EMB / 4);
  transpose_cast_kernel<<<dim3(DFF / 64, D_EMB / 64, N_EXP), 256, 0, stream>>>(wfc, wfcT, D_EMB, DFF);
  transpose_cast_kernel<<<dim3(D_EMB / 64, DFF / 64, N_EXP), 256, 0, stream>>>(wpj, wpjT, DFF, D_EMB);
  gate_kernel<<<T_TOK / 16, 256, 0, stream>>>(x, gw, cnt, tok, wgt);
  plan_kernel<<<1, 1, 0, stream>>>(cnt, offs, tile_e, tile_rt, ntiles);
  // FC: K=768 (NKT=24), N=3072, no split-K. grid = 72*24 = 1728 (%8==0)
  moe_gemm<D_EMB, DFF, 1, 0><<<MAXT * (DFF / 128), 256, 0, stream>>>(
      xb, wfcT, tok, wgt, cnt, offs, tile_e, tile_rt, ntiles, h, nullptr);
  // PROJ: K=3072 split 2 ways (NKT=48 each), N=768. grid = 2*72*6 = 864 (%8==0)
  moe_gemm<DFF, D_EMB, 2, 1><<<2 * MAXT * (D_EMB / 128), 256, 0, stream>>>(
      h, wpjT, tok, wgt, cnt, offs, tile_e, tile_rt, ntiles, nullptr, out);
}